// Round 12
// baseline (2119.493 us; speedup 1.0000x reference)
//
#include <hip/hip_runtime.h>
#include <hip/hip_fp16.h>
#include <hip/hip_cooperative_groups.h>
namespace cg = cooperative_groups;

#define N_NODES 100000
#define N_EDGES 1200000
#define GRAPHS 128
#define EPSBN 1e-5f
#define HG_G 32     // histogram blocks per segment
#define HG_SEG 4    // segments of 25000 bins (100 KB LDS each)
#define HG_BINS 25000

// ---------------- out-degree histogram: LDS-privatized, no global atomics ----------------

__global__ __launch_bounds__(256) void k_hist(const int* __restrict__ src,
                                              int* __restrict__ pdeg) {
    __shared__ int bins[HG_BINS];
    int t = threadIdx.x;
    int seg = blockIdx.x / HG_G, g = blockIdx.x % HG_G;
    for (int i = t; i < HG_BINS; i += 256) bins[i] = 0;
    __syncthreads();
    int lo = seg * HG_BINS, hi = lo + HG_BINS;
    const int chunk = N_EDGES / HG_G;   // 37500 exact
    int e0 = g * chunk, e1 = e0 + chunk;
    for (int e = e0 + t; e < e1; e += 256) {
        int s = src[e];
        if (s >= lo && s < hi) atomicAdd(&bins[s - lo], 1);
    }
    __syncthreads();
    for (int i = t; i < HG_BINS; i += 256)
        pdeg[(seg * HG_G + g) * HG_BINS + i] = bins[i];
}

// ---------------- phase helpers (inlined into k_mega) ----------------

__device__ __forceinline__ void gemm_phase(const float* __restrict__ X,
        const float* __restrict__ sums, const float* __restrict__ bng,
        const float* __restrict__ bnb, const float* __restrict__ W,
        const float* __restrict__ bias_in,
        float* __restrict__ Y, __half* __restrict__ Yh,
        int relu, const float* __restrict__ scale,
        float* __restrict__ sums_out, int do_stats,
        int nb, int bid, int t, float* smem)
{
    int j = t & 63, rg = t >> 6;
    float* aa = smem; float* cc = smem + 64; float* xs = smem + 128;  // xs[16][64]
    if (t < 64) {
        float mu = sums[t] * (1.0f / N_NODES);
        float var = sums[64 + t] * (1.0f / N_NODES) - mu * mu;
        float av = bng[t] * rsqrtf(var + EPSBN);
        aa[t] = av; cc[t] = bnb[t] - mu * av;
    }
    __syncthreads();
    float wreg[64];
    float bj = bias_in ? bias_in[j] : 0.0f;
#pragma unroll
    for (int c = 0; c < 64; c++) {
        float w = W[c * 64 + j];
        wreg[c] = w * aa[c];
        bj += cc[c] * w;
    }
    float s_sum = 0.f, s_sq = 0.f;
    for (int base = bid * 16; base < N_NODES; base += nb * 16) {
        __syncthreads();
        ((float4*)xs)[t] = ((const float4*)(X + base * 64))[t];
        __syncthreads();
        int r0 = rg * 4;
        float a0 = bj, a1 = bj, a2 = bj, a3 = bj;
#pragma unroll
        for (int c = 0; c < 64; c++) {
            float w = wreg[c];
            a0 += xs[(r0 + 0) * 64 + c] * w;
            a1 += xs[(r0 + 1) * 64 + c] * w;
            a2 += xs[(r0 + 2) * 64 + c] * w;
            a3 += xs[(r0 + 3) * 64 + c] * w;
        }
        if (relu) {
            a0 = fmaxf(a0, 0.f); a1 = fmaxf(a1, 0.f);
            a2 = fmaxf(a2, 0.f); a3 = fmaxf(a3, 0.f);
        }
        if (scale) {
            a0 *= scale[base + r0 + 0];
            a1 *= scale[base + r0 + 1];
            a2 *= scale[base + r0 + 2];
            a3 *= scale[base + r0 + 3];
        }
        if (Yh) {
            Yh[(base + r0 + 0) * 64 + j] = __float2half_rn(a0);
            Yh[(base + r0 + 1) * 64 + j] = __float2half_rn(a1);
            Yh[(base + r0 + 2) * 64 + j] = __float2half_rn(a2);
            Yh[(base + r0 + 3) * 64 + j] = __float2half_rn(a3);
        } else {
            Y[(base + r0 + 0) * 64 + j] = a0;
            Y[(base + r0 + 1) * 64 + j] = a1;
            Y[(base + r0 + 2) * 64 + j] = a2;
            Y[(base + r0 + 3) * 64 + j] = a3;
        }
        if (do_stats) {
            s_sum += a0 + a1 + a2 + a3;
            s_sq += a0 * a0 + a1 * a1 + a2 * a2 + a3 * a3;
        }
    }
    if (do_stats) {
        __syncthreads();
        xs[rg * 64 + j] = s_sum;
        xs[(4 + rg) * 64 + j] = s_sq;
        __syncthreads();
        if (t < 64) {
            atomicAdd(&sums_out[t], xs[t] + xs[64 + t] + xs[128 + t] + xs[192 + t]);
            atomicAdd(&sums_out[64 + t], xs[256 + t] + xs[320 + t] + xs[384 + t] + xs[448 + t]);
        }
    }
    __syncthreads();
}

__device__ __forceinline__ void agg_phase(const __half* __restrict__ hws,
        const float* __restrict__ dis, const int* __restrict__ cnt,
        const int* __restrict__ ecsr, const float* __restrict__ bias,
        float* __restrict__ hout, float* __restrict__ sums, int do_stats,
        int nb, int bid, int tt, float* smem)
{
    const __half2* hw2 = (const __half2*)hws;
    int lane = tt & 63, wid = tt >> 6;
    int g = lane >> 5, c = lane & 31;
    float2 bias2 = ((const float2*)bias)[c];
    float2 ssum = {0.f, 0.f}, ssq = {0.f, 0.f};
    for (int node = bid * 4 + wid; node < N_NODES; node += nb * 4) {
        int m = cnt[node];
        int sraw = ecsr[(node << 6) + lane];
        int sL = (lane < m) ? sraw : 0;
        float ax = 0.f, ay = 0.f;
#pragma unroll
        for (int k = 0; k < 8; k++) {
            int e = 2 * k + g;
            int sE = __shfl(sL, e, 64);
            float w = (e < m) ? 1.0f : 0.0f;
            float2 f = __half22float2(hw2[sE * 32 + c]);
            ax += w * f.x; ay += w * f.y;
        }
        if (m > 16) {
            for (int e = 16 + g; e < m; e += 2) {
                int sE = __shfl(sL, e, 64);
                float2 f = __half22float2(hw2[sE * 32 + c]);
                ax += f.x; ay += f.y;
            }
        }
        ax += __shfl_xor(ax, 32, 64);
        ay += __shfl_xor(ay, 32, 64);
        if (g == 0) {
            float2 sf = __half22float2(hw2[node * 32 + c]);
            float dd = dis[node];
            float hx = fmaxf(dd * (ax + sf.x) + bias2.x, 0.f);
            float hy = fmaxf(dd * (ay + sf.y) + bias2.y, 0.f);
            float2 h2v; h2v.x = hx; h2v.y = hy;
            ((float2*)hout)[node * 32 + c] = h2v;
            if (do_stats) {
                ssum.x += hx; ssum.y += hy;
                ssq.x += hx * hx; ssq.y += hy * hy;
            }
        }
    }
    if (do_stats) {
        float* red = smem;   // [2][4][64] = 512 floats
        if (g == 0) {
            red[wid * 64 + 2 * c + 0] = ssum.x; red[wid * 64 + 2 * c + 1] = ssum.y;
            red[256 + wid * 64 + 2 * c + 0] = ssq.x; red[256 + wid * 64 + 2 * c + 1] = ssq.y;
        }
        __syncthreads();
        if (tt < 64) {
            atomicAdd(&sums[tt], red[tt] + red[64 + tt] + red[128 + tt] + red[192 + tt]);
            atomicAdd(&sums[64 + tt], red[256 + tt] + red[320 + tt] + red[384 + tt] + red[448 + tt]);
        }
    }
    __syncthreads();
}

// ---------------- the cooperative mega-kernel: whole graph pipeline, one dispatch ----------------

__global__ __launch_bounds__(256, 4) void k_mega(
    const int* __restrict__ src, const int* __restrict__ dst,
    const float* __restrict__ x,
    const float* __restrict__ bn_feat_g, const float* __restrict__ bn_feat_b,
    const float* __restrict__ W_feat, const float* __restrict__ b_feat,
    const float* __restrict__ conv_bn_g, const float* __restrict__ conv_bn_b,
    const float* __restrict__ conv_W, const float* __restrict__ conv_b,
    const int* __restrict__ batch,
    int* __restrict__ cnt, int* __restrict__ ecsr,
    const int* __restrict__ pdeg, float* __restrict__ dis,
    float* __restrict__ hbuf, __half* __restrict__ hws,
    float* __restrict__ hg, float* __restrict__ sums)
{
    cg::grid_group grid = cg::this_grid();
    __shared__ float smem[2176];
    int nb = gridDim.x, bid = blockIdx.x, t = threadIdx.x;

    // ---- P0: zero cnt, sums, hg ----
    for (int k = bid * 256 + t; k < N_NODES; k += nb * 256) cnt[k] = 0;
    for (int k = bid * 256 + t; k < 640 + 8192; k += nb * 256) {
        if (k < 640) sums[k] = 0.f; else hg[k - 640] = 0.f;
    }
    grid.sync();

    // ---- P1: CSR bucket build (blocks [0, nb-128)) + x stats (blocks [nb-128, nb)) ----
    if (bid < nb - 128) {
        int nbb = nb - 128;
        for (int e = bid * 256 + t; e < N_EDGES; e += nbb * 256) {
            int s = src[e], d = dst[e];
            int p = atomicAdd(&cnt[d], 1);
            __builtin_nontemporal_store(s, &ecsr[(d << 6) + p]);
        }
    } else {
        int sid = bid - (nb - 128);
        const float4* x4 = (const float4*)x;
        int q = t & 15, rg = t >> 4;
        float4 s = {0.f,0.f,0.f,0.f}, s2 = {0.f,0.f,0.f,0.f};
        for (int r = sid * 16 + rg; r < N_NODES; r += 128 * 16) {
            float4 v = x4[r * 16 + q];
            s.x += v.x; s.y += v.y; s.z += v.z; s.w += v.w;
            s2.x += v.x*v.x; s2.y += v.y*v.y; s2.z += v.z*v.z; s2.w += v.w*v.w;
        }
        float* red = smem;   // [2][16][64] = 2048
        red[rg * 64 + q*4+0] = s.x;  red[rg * 64 + q*4+1] = s.y;
        red[rg * 64 + q*4+2] = s.z;  red[rg * 64 + q*4+3] = s.w;
        red[1024 + rg * 64 + q*4+0] = s2.x; red[1024 + rg * 64 + q*4+1] = s2.y;
        red[1024 + rg * 64 + q*4+2] = s2.z; red[1024 + rg * 64 + q*4+3] = s2.w;
        __syncthreads();
        if (t < 64) {
            float a = 0.f, b = 0.f;
#pragma unroll
            for (int k = 0; k < 16; k++) { a += red[k * 64 + t]; b += red[1024 + k * 64 + t]; }
            atomicAdd(&sums[t], a);
            atomicAdd(&sums[64 + t], b);
        }
    }
    grid.sync();

    // ---- P2: degsum (pdeg -> dis) + feature GEMM (BN fold inline, relu, stats -> s0) ----
    for (int task = bid; task * 256 < N_NODES; task += nb) {
        int i = task * 256 + t;
        if (i < N_NODES) {
            int seg = i / HG_BINS, loc = i - seg * HG_BINS;
            int sdeg = 0;
#pragma unroll
            for (int g2 = 0; g2 < HG_G; g2++) sdeg += pdeg[(seg * HG_G + g2) * HG_BINS + loc];
            dis[i] = rsqrtf((float)sdeg + 1.0f);   // +1 self-loop
        }
    }
    gemm_phase(x, sums, bn_feat_g, bn_feat_b, W_feat, b_feat,
               hbuf, nullptr, 1, nullptr, sums + 128, 1, nb, bid, t, smem);
    grid.sync();

    // ---- P3..P8: 3 x (GEMM -> agg) ----
    for (int l = 0; l < 3; l++) {
        gemm_phase(hbuf, sums + 128 * (l + 1), conv_bn_g + l * 64, conv_bn_b + l * 64,
                   conv_W + l * 4096, nullptr, nullptr, hws, 0, dis,
                   nullptr, 0, nb, bid, t, smem);
        grid.sync();
        agg_phase(hws, dis, cnt, ecsr, conv_b + l * 64, hbuf,
                  sums + 128 * (l + 2), (l < 2) ? 1 : 0, nb, bid, t, smem);
        grid.sync();
    }

    // ---- P9: pool (8 blocks per graph, atomic partials into hg) ----
    for (int task = bid; task < GRAPHS * 8; task += nb) {
        int g = task >> 3, sub = task & 7;
        int lo = 0, hi = N_NODES;
        while (lo < hi) { int m = (lo + hi) >> 1; if (batch[m] < g) lo = m + 1; else hi = m; }
        int start = lo;
        lo = start; hi = N_NODES;
        while (lo < hi) { int m = (lo + hi) >> 1; if (batch[m] < g + 1) lo = m + 1; else hi = m; }
        int end = lo;
        int len = end - start;
        int r0 = start + (len * sub) / 8;
        int r1 = start + (len * (sub + 1)) / 8;
        int c = t & 63, rg = t >> 6;
        float s = 0.f;
        for (int r = r0 + rg; r < r1; r += 4) s += hbuf[r * 64 + c];
        __syncthreads();
        smem[rg * 64 + c] = s;
        __syncthreads();
        if (rg == 0)
            atomicAdd(&hg[g * 64 + c], smem[c] + smem[64 + c] + smem[128 + c] + smem[192 + c]);
        __syncthreads();
    }
}

// ---------------- tail: BN(stats in-LDS) -> FC+relu -> BN -> classifier -> log_softmax ----------------

__global__ __launch_bounds__(512) void k_tail(const float* __restrict__ hg_in,
                       const float* __restrict__ g1, const float* __restrict__ b1,
                       const float* __restrict__ Wfc, const float* __restrict__ bfc,
                       const float* __restrict__ g2, const float* __restrict__ b2,
                       const float* __restrict__ Wcls, const float* __restrict__ bcls,
                       float* __restrict__ out) {
    __shared__ float hgn[8192];
    __shared__ float h2[8192];
    __shared__ float red[2][8][64];
    __shared__ float a[64], cc[64];
    __shared__ float Wc[640];
    __shared__ float logits[1280];
    __shared__ float lse[128];
    int t = threadIdx.x;
    int j = t & 63;
    int w = t >> 6;

    for (int i = t; i < 8192; i += 512) hgn[i] = hg_in[i];
    for (int i = t; i < 640; i += 512) Wc[i] = Wcls[i];
    __syncthreads();
    // BN1 stats from hgn (pool no longer produces them)
    {
        float s = 0.f, s2 = 0.f;
        for (int r = w; r < 128; r += 8) { float v = hgn[r * 64 + j]; s += v; s2 += v * v; }
        red[0][w][j] = s; red[1][w][j] = s2;
    }
    __syncthreads();
    if (t < 64) {
        float su = 0.f, sq = 0.f;
#pragma unroll
        for (int k = 0; k < 8; k++) { su += red[0][k][t]; sq += red[1][k][t]; }
        float mu = su * (1.f / 128.f);
        float var = sq * (1.f / 128.f) - mu * mu;
        float av = g1[t] * rsqrtf(var + EPSBN);
        a[t] = av; cc[t] = b1[t] - mu * av;
    }
    __syncthreads();
    for (int i = t; i < 8192; i += 512) hgn[i] = hgn[i] * a[i & 63] + cc[i & 63];

    float wreg[64];
#pragma unroll
    for (int q = 0; q < 64; q++) wreg[q] = Wfc[q * 64 + j];
    float bj = bfc[j];
    __syncthreads();

    float acc[16];
#pragma unroll
    for (int r = 0; r < 16; r++) acc[r] = bj;
    const float4* hgn4 = (const float4*)hgn;
#pragma unroll
    for (int q4 = 0; q4 < 16; q4++) {
#pragma unroll
        for (int r = 0; r < 16; r++) {
            float4 hv = hgn4[(w * 16 + r) * 16 + q4];
            acc[r] += hv.x * wreg[q4 * 4 + 0] + hv.y * wreg[q4 * 4 + 1]
                    + hv.z * wreg[q4 * 4 + 2] + hv.w * wreg[q4 * 4 + 3];
        }
    }
    float s = 0.f, s2 = 0.f;
#pragma unroll
    for (int r = 0; r < 16; r++) {
        float v = fmaxf(acc[r], 0.f);
        h2[(w * 16 + r) * 64 + j] = v;
        s += v; s2 += v * v;
    }
    red[0][w][j] = s; red[1][w][j] = s2;
    __syncthreads();

    if (t < 64) {
        float su = 0.f, sq = 0.f;
#pragma unroll
        for (int k = 0; k < 8; k++) { su += red[0][k][t]; sq += red[1][k][t]; }
        float mu = su * (1.f / 128.f);
        float var = sq * (1.f / 128.f) - mu * mu;
        float av = g2[t] * rsqrtf(var + EPSBN);
        a[t] = av; cc[t] = b2[t] - mu * av;
    }
    __syncthreads();
    for (int i = t; i < 8192; i += 512) h2[i] = h2[i] * a[i & 63] + cc[i & 63];
    __syncthreads();

    for (int idx = t; idx < 1280; idx += 512) {
        int row = idx / 10, o = idx - row * 10;
        float v = bcls[o];
#pragma unroll
        for (int q = 0; q < 64; q++) v += h2[row * 64 + q] * Wc[q * 10 + o];
        logits[idx] = v;
    }
    __syncthreads();
    if (t < 128) {
        float mx = -1e30f;
#pragma unroll
        for (int o = 0; o < 10; o++) mx = fmaxf(mx, logits[t * 10 + o]);
        float se = 0.f;
#pragma unroll
        for (int o = 0; o < 10; o++) se += expf(logits[t * 10 + o] - mx);
        lse[t] = mx + logf(se);
    }
    __syncthreads();
    for (int idx = t; idx < 1280; idx += 512) out[idx] = logits[idx] - lse[idx / 10];
}

// ---------------- launcher ----------------

extern "C" void kernel_launch(void* const* d_in, const int* in_sizes, int n_in,
                              void* d_out, int out_size, void* d_ws, size_t ws_size,
                              hipStream_t stream) {
    const float* x         = (const float*)d_in[0];
    const int*   ei        = (const int*)  d_in[1];
    const int*   batch     = (const int*)  d_in[2];
    const float* bn_feat_g = (const float*)d_in[3];
    const float* bn_feat_b = (const float*)d_in[4];
    const float* W_feat    = (const float*)d_in[5];
    const float* b_feat    = (const float*)d_in[6];
    const float* conv_bn_g = (const float*)d_in[7];
    const float* conv_bn_b = (const float*)d_in[8];
    const float* conv_W    = (const float*)d_in[9];
    const float* conv_b    = (const float*)d_in[10];
    const float* bn_fc_g   = (const float*)d_in[11];
    const float* bn_fc_b   = (const float*)d_in[12];
    const float* W_fc      = (const float*)d_in[13];
    const float* b_fc      = (const float*)d_in[14];
    const float* bn_hid_g  = (const float*)d_in[15];
    const float* bn_hid_b  = (const float*)d_in[16];
    const float* W_cls     = (const float*)d_in[17];
    const float* b_cls     = (const float*)d_in[18];
    float* out = (float*)d_out;

    float* ws   = (float*)d_ws;
    float* hbuf = ws;                         // 6,400,000 f
    __half* hws = (__half*)(ws + 6400000);    // 6,400,000 halves = 3,200,000 f-slots
    float* dis  = ws + 9600000;               // 100,000 f
    float* hg   = ws + 9700000;               // 8192 f
    float* sums = hg + 8192;                  // 640 f  (sx, s0, s1, s2, spare)
    int*   cnt  = (int*)(sums + 640);         // 100,000 i
    int*   ecsr = cnt + 100000;               // 6,400,000 i (100k * 64)
    int*   pdeg = (int*)hws;                  // 3,200,000 i scratch; dead before hws written

    const int* srcp = ei;
    const int* dstp = ei + N_EDGES;

    // out-degree histogram (100 KB LDS, separate launch)
    k_hist<<<HG_SEG * HG_G, 256, 0, stream>>>(srcp, pdeg);

    // cooperative mega-kernel: grid sized for guaranteed co-residency
    int maxB = 0;
    hipOccupancyMaxActiveBlocksPerMultiprocessor(&maxB, k_mega, 256, 0);
    int grid = maxB * 256;           // 256 CUs on MI355X
    if (grid > 1024) grid = 1024;
    if (grid < 256) grid = 256;      // need > 128 for the build/stats split

    const int* pdeg_c = pdeg;
    void* args[] = {
        (void*)&srcp, (void*)&dstp, (void*)&x,
        (void*)&bn_feat_g, (void*)&bn_feat_b, (void*)&W_feat, (void*)&b_feat,
        (void*)&conv_bn_g, (void*)&conv_bn_b, (void*)&conv_W, (void*)&conv_b,
        (void*)&batch,
        (void*)&cnt, (void*)&ecsr, (void*)&pdeg_c, (void*)&dis,
        (void*)&hbuf, (void*)&hws, (void*)&hg, (void*)&sums
    };
    hipLaunchCooperativeKernel((void*)k_mega, dim3(grid), dim3(256), args, 0, stream);

    // tail (BN1 stats computed in-kernel from hg)
    k_tail<<<1, 512, 0, stream>>>(hg, bn_fc_g, bn_fc_b, W_fc, b_fc,
                                  bn_hid_g, bn_hid_b, W_cls, b_cls, out);
}

// Round 13
// 691.014 us; speedup vs baseline: 3.0672x; 3.0672x over previous
//
#include <hip/hip_runtime.h>
#include <hip/hip_fp16.h>

#define N_NODES 100000
#define N_EDGES 1200000
#define GRAPHS 128
#define EPSBN 1e-5f
#define HG_G 32     // histogram blocks per segment
#define HG_SEG 4    // segments of 25000 bins (100 KB LDS each)
#define HG_BINS 25000

// ---------------- bucketed CSR build: ONE atomic per edge ----------------

__global__ __launch_bounds__(256) void k_build(const int* __restrict__ src,
                                               const int* __restrict__ dst,
                                               int* __restrict__ cnt,
                                               int* __restrict__ ecsr) {
    int e = blockIdx.x * 256 + threadIdx.x;
    if (e < N_EDGES) {
        int s = src[e], d = dst[e];
        int p = atomicAdd(&cnt[d], 1);
        ecsr[(d << 6) + p] = s;
    }
}

// ---------------- out-degree histogram: LDS-privatized, no global atomics ----------------

__global__ __launch_bounds__(256) void k_hist(const int* __restrict__ src,
                                              int* __restrict__ pdeg) {
    __shared__ int bins[HG_BINS];
    int t = threadIdx.x;
    int seg = blockIdx.x / HG_G, g = blockIdx.x % HG_G;
    for (int i = t; i < HG_BINS; i += 256) bins[i] = 0;
    __syncthreads();
    int lo = seg * HG_BINS, hi = lo + HG_BINS;
    const int chunk = N_EDGES / HG_G;   // 37500 exact
    int e0 = g * chunk, e1 = e0 + chunk;
    for (int e = e0 + t; e < e1; e += 256) {
        int s = src[e];
        if (s >= lo && s < hi) atomicAdd(&bins[s - lo], 1);
    }
    __syncthreads();
    for (int i = t; i < HG_BINS; i += 256)
        pdeg[(seg * HG_G + g) * HG_BINS + i] = bins[i];
}

__global__ __launch_bounds__(256) void k_degsum(const int* __restrict__ pdeg,
                                                float* __restrict__ dis) {
    int i = blockIdx.x * 256 + threadIdx.x;
    if (i >= N_NODES) return;
    int seg = i / HG_BINS, loc = i - seg * HG_BINS;
    int s = 0;
#pragma unroll
    for (int g = 0; g < HG_G; g++) s += pdeg[(seg * HG_G + g) * HG_BINS + loc];
    dis[i] = rsqrtf((float)s + 1.0f);   // +1 self-loop
}

// ---------------- BN stats over x: float4 loads, LDS reduce ----------------

__global__ __launch_bounds__(256) void k_stats(const float* __restrict__ x,
                                               float* __restrict__ sums) {
    const float4* x4 = (const float4*)x;
    int t = threadIdx.x;
    int q = t & 15, rg = t >> 4;
    float4 s = {0.f, 0.f, 0.f, 0.f}, s2 = {0.f, 0.f, 0.f, 0.f};
    for (int r = blockIdx.x * 16 + rg; r < N_NODES; r += gridDim.x * 16) {
        float4 v = x4[r * 16 + q];
        s.x += v.x; s.y += v.y; s.z += v.z; s.w += v.w;
        s2.x += v.x * v.x; s2.y += v.y * v.y; s2.z += v.z * v.z; s2.w += v.w * v.w;
    }
    __shared__ float red[2][16][64];
    red[0][rg][q * 4 + 0] = s.x;  red[0][rg][q * 4 + 1] = s.y;
    red[0][rg][q * 4 + 2] = s.z;  red[0][rg][q * 4 + 3] = s.w;
    red[1][rg][q * 4 + 0] = s2.x; red[1][rg][q * 4 + 1] = s2.y;
    red[1][rg][q * 4 + 2] = s2.z; red[1][rg][q * 4 + 3] = s2.w;
    __syncthreads();
    if (t < 64) {
        float a = 0.f, b = 0.f;
#pragma unroll
        for (int k = 0; k < 16; k++) { a += red[0][k][t]; b += red[1][k][t]; }
        atomicAdd(&sums[t], a);
        atomicAdd(&sums[64 + t], b);
    }
}

// ---------------- fold BN into GEMM: W' = diag(a)W, b' = c@W (+bias) ----------------

__global__ __launch_bounds__(256) void k_fold(const float* __restrict__ sums, const float* __restrict__ g,
                       const float* __restrict__ b, const float* __restrict__ W,
                       const float* __restrict__ bias_in, int has_bias,
                       float* __restrict__ Wout, float* __restrict__ bout) {
    __shared__ float a[64], cc[64];
    int t = threadIdx.x;
    if (t < 64) {
        float mu = sums[t] * (1.0f / N_NODES);
        float var = sums[64 + t] * (1.0f / N_NODES) - mu * mu;
        float av = g[t] * rsqrtf(var + EPSBN);
        a[t] = av;
        cc[t] = b[t] - mu * av;
    }
    __syncthreads();
    for (int i = t; i < 4096; i += 256) Wout[i] = a[i >> 6] * W[i];
    if (t < 64) {
        float acc = has_bias ? bias_in[t] : 0.0f;
        for (int k = 0; k < 64; k++) acc += cc[k] * W[k * 64 + t];
        bout[t] = acc;
    }
}

// ---------------- feature GEMM: Y = X@W + bias, relu, fused output stats ----------------

__global__ __launch_bounds__(256) void k_gemm2(const float* __restrict__ X, const float* __restrict__ W,
                        const float* __restrict__ bias, float* __restrict__ Y,
                        float* __restrict__ sums, int do_stats) {
    int t = threadIdx.x;
    int j = t & 63;
    int rg = t >> 6;
    float wreg[64];
#pragma unroll
    for (int c = 0; c < 64; c++) wreg[c] = W[c * 64 + j];
    float bj = bias[j];
    __shared__ float xs[16][64];
    float s_sum = 0.f, s_sq = 0.f;
    for (int base = blockIdx.x * 16; base < N_NODES; base += gridDim.x * 16) {
        __syncthreads();
        ((float4*)xs)[t] = ((const float4*)(X + base * 64))[t];
        __syncthreads();
        int r0 = rg * 4;
        float a0 = bj, a1 = bj, a2 = bj, a3 = bj;
#pragma unroll
        for (int c = 0; c < 64; c++) {
            float w = wreg[c];
            a0 += xs[r0 + 0][c] * w;
            a1 += xs[r0 + 1][c] * w;
            a2 += xs[r0 + 2][c] * w;
            a3 += xs[r0 + 3][c] * w;
        }
        a0 = fmaxf(a0, 0.f); a1 = fmaxf(a1, 0.f);
        a2 = fmaxf(a2, 0.f); a3 = fmaxf(a3, 0.f);
        Y[(base + r0 + 0) * 64 + j] = a0;
        Y[(base + r0 + 1) * 64 + j] = a1;
        Y[(base + r0 + 2) * 64 + j] = a2;
        Y[(base + r0 + 3) * 64 + j] = a3;
        if (do_stats) {
            s_sum += a0 + a1 + a2 + a3;
            s_sq += a0 * a0 + a1 * a1 + a2 * a2 + a3 * a3;
        }
    }
    if (do_stats) {
        __syncthreads();
        xs[rg][j] = s_sum;
        xs[4 + rg][j] = s_sq;
        __syncthreads();
        if (t < 64) {
            atomicAdd(&sums[t], xs[0][t] + xs[1][t] + xs[2][t] + xs[3][t]);
            atomicAdd(&sums[64 + t], xs[4][t] + xs[5][t] + xs[6][t] + xs[7][t]);
        }
    }
}

// ---------------- u = dis * BN(h): elementwise fp16 prep for aggregation ----------------

__global__ __launch_bounds__(256) void k_uprep(const float* __restrict__ h,
                        const float* __restrict__ sums, const float* __restrict__ bng,
                        const float* __restrict__ bnb, const float* __restrict__ dis,
                        __half* __restrict__ u) {
    __shared__ float aa[64], cc[64];
    int t = threadIdx.x;
    if (t < 64) {
        float mu = sums[t] * (1.0f / N_NODES);
        float var = sums[64 + t] * (1.0f / N_NODES) - mu * mu;
        float av = bng[t] * rsqrtf(var + EPSBN);
        aa[t] = av; cc[t] = bnb[t] - mu * av;
    }
    __syncthreads();
    int q = t & 15, rg = t >> 4;
    const float4* h4 = (const float4*)h;
    float2* u8 = (float2*)u;   // 8 B = 4 halves
    float a0 = aa[q * 4 + 0], a1 = aa[q * 4 + 1], a2 = aa[q * 4 + 2], a3 = aa[q * 4 + 3];
    float c0 = cc[q * 4 + 0], c1 = cc[q * 4 + 1], c2 = cc[q * 4 + 2], c3 = cc[q * 4 + 3];
    for (int r = blockIdx.x * 16 + rg; r < N_NODES; r += gridDim.x * 16) {
        float4 v = h4[r * 16 + q];
        float dd = dis[r];
        __half2 o01, o23;
        o01.x = __float2half_rn(dd * (v.x * a0 + c0));
        o01.y = __float2half_rn(dd * (v.y * a1 + c1));
        o23.x = __float2half_rn(dd * (v.z * a2 + c2));
        o23.y = __float2half_rn(dd * (v.w * a3 + c3));
        float2 pk;
        pk.x = *reinterpret_cast<float*>(&o01);
        pk.y = *reinterpret_cast<float*>(&o23);
        u8[r * 16 + q] = pk;
    }
}

// ---------------- fused agg+GEMM (commuted GCN): h_out = relu( (S u) @ W + b ) ----------------
// agg result row for node d: dis[d] * (sum_e u[src_e] + u[d])  -> wave-private LDS -> 64x64 GEMM
// gather core = R10's half2 pattern (2 edge subgroups x 32 channel pairs, 8 loads in flight)

__global__ __launch_bounds__(256) void k_aggemm(const __half* __restrict__ u,
                        const float* __restrict__ dis,
                        const int* __restrict__ cnt, const int* __restrict__ ecsr,
                        const float* __restrict__ W, const float* __restrict__ bias,
                        float* __restrict__ hout,
                        float* __restrict__ sums_out, int do_stats) {
    const __half2* u2 = (const __half2*)u;
    int t = threadIdx.x;
    int j = t & 63;           // lane; also output column in GEMM phase
    int wid = t >> 6;
    int g = j >> 5, c = j & 31;
    float wreg[64];
#pragma unroll
    for (int q = 0; q < 64; q++) wreg[q] = W[q * 64 + j];
    float bj = bias[j];
    __shared__ float xs[16][64];   // wave w owns rows 4w..4w+3 (wave-private, no barriers in loop)
    float s_sum = 0.f, s_sq = 0.f;
    // N_NODES % 16 == 0, so no bounds checks inside the tile
    for (int base = blockIdx.x * 16; base < N_NODES; base += gridDim.x * 16) {
        int r0 = wid * 4;
        // ---- phase A: aggregate 4 nodes into wave-private xs rows ----
        for (int r = 0; r < 4; r++) {
            int node = base + r0 + r;
            int m = cnt[node];
            int sraw = ecsr[(node << 6) + j];     // unconditional: bucket always 64-wide
            int sL = (j < m) ? sraw : 0;
            float ax = 0.f, ay = 0.f;
#pragma unroll
            for (int k = 0; k < 8; k++) {         // 8 independent 4-B gathers per lane
                int e = 2 * k + g;
                int sE = __shfl(sL, e, 64);
                float w = (e < m) ? 1.0f : 0.0f;
                float2 f = __half22float2(u2[sE * 32 + c]);
                ax += w * f.x; ay += w * f.y;
            }
            if (m > 16) {                          // rare wave-uniform extension
                for (int e = 16 + g; e < m; e += 2) {
                    int sE = __shfl(sL, e, 64);
                    float2 f = __half22float2(u2[sE * 32 + c]);
                    ax += f.x; ay += f.y;
                }
            }
            ax += __shfl_xor(ax, 32, 64);
            ay += __shfl_xor(ay, 32, 64);
            if (g == 0) {
                float2 sf = __half22float2(u2[node * 32 + c]);   // self-loop term
                float dd = dis[node];
                xs[r0 + r][2 * c + 0] = dd * (ax + sf.x);
                xs[r0 + r][2 * c + 1] = dd * (ay + sf.y);
            }
        }
        // ---- phase B: GEMM the wave's 4 rows (LDS written+read by same wave) ----
        float a0 = bj, a1 = bj, a2 = bj, a3 = bj;
#pragma unroll
        for (int q = 0; q < 64; q++) {
            float w = wreg[q];
            a0 += xs[r0 + 0][q] * w;
            a1 += xs[r0 + 1][q] * w;
            a2 += xs[r0 + 2][q] * w;
            a3 += xs[r0 + 3][q] * w;
        }
        a0 = fmaxf(a0, 0.f); a1 = fmaxf(a1, 0.f);
        a2 = fmaxf(a2, 0.f); a3 = fmaxf(a3, 0.f);
        hout[(base + r0 + 0) * 64 + j] = a0;
        hout[(base + r0 + 1) * 64 + j] = a1;
        hout[(base + r0 + 2) * 64 + j] = a2;
        hout[(base + r0 + 3) * 64 + j] = a3;
        if (do_stats) {
            s_sum += a0 + a1 + a2 + a3;
            s_sq += a0 * a0 + a1 * a1 + a2 * a2 + a3 * a3;
        }
    }
    if (do_stats) {
        __syncthreads();
        xs[wid][j] = s_sum;
        xs[4 + wid][j] = s_sq;
        __syncthreads();
        if (t < 64) {
            atomicAdd(&sums_out[t], xs[0][t] + xs[1][t] + xs[2][t] + xs[3][t]);
            atomicAdd(&sums_out[64 + t], xs[4][t] + xs[5][t] + xs[6][t] + xs[7][t]);
        }
    }
}

// ---------------- global_add_pool + fused BN-fc stats ----------------

__global__ __launch_bounds__(256) void k_pool(const float* __restrict__ h, const int* __restrict__ batch,
                       float* __restrict__ hg, float* __restrict__ sums) {
    int g = blockIdx.x;
    int lo = 0, hi = N_NODES;
    while (lo < hi) { int m = (lo + hi) >> 1; if (batch[m] < g) lo = m + 1; else hi = m; }
    int start = lo;
    lo = start; hi = N_NODES;
    while (lo < hi) { int m = (lo + hi) >> 1; if (batch[m] < g + 1) lo = m + 1; else hi = m; }
    int end = lo;
    int c = threadIdx.x & 63, rg = threadIdx.x >> 6;
    float s = 0.f;
    for (int r = start + rg; r < end; r += 4) s += h[r * 64 + c];
    __shared__ float ls[4][64];
    ls[rg][c] = s;
    __syncthreads();
    if (rg == 0) {
        float v = ls[0][c] + ls[1][c] + ls[2][c] + ls[3][c];
        hg[g * 64 + c] = v;
        atomicAdd(&sums[c], v);
        atomicAdd(&sums[64 + c], v * v);
    }
}

// ---------------- tail: BN -> FC+relu -> BN -> classifier -> log_softmax ----------------

__global__ __launch_bounds__(512) void k_tail(const float* __restrict__ hg_in, const float* __restrict__ sums,
                       const float* __restrict__ g1, const float* __restrict__ b1,
                       const float* __restrict__ Wfc, const float* __restrict__ bfc,
                       const float* __restrict__ g2, const float* __restrict__ b2,
                       const float* __restrict__ Wcls, const float* __restrict__ bcls,
                       float* __restrict__ out) {
    __shared__ float hgn[8192];
    __shared__ float h2[8192];
    __shared__ float red[2][8][64];
    __shared__ float a[64], cc[64];
    __shared__ float Wc[640];
    __shared__ float logits[1280];
    __shared__ float lse[128];
    int t = threadIdx.x;
    int j = t & 63;
    int w = t >> 6;

    if (t < 64) {
        float mu = sums[t] * (1.f / 128.f);
        float var = sums[64 + t] * (1.f / 128.f) - mu * mu;
        float av = g1[t] * rsqrtf(var + EPSBN);
        a[t] = av; cc[t] = b1[t] - mu * av;
    }
    for (int i = t; i < 640; i += 512) Wc[i] = Wcls[i];
    __syncthreads();
    for (int i = t; i < 8192; i += 512) hgn[i] = hg_in[i] * a[i & 63] + cc[i & 63];

    float wreg[64];
#pragma unroll
    for (int q = 0; q < 64; q++) wreg[q] = Wfc[q * 64 + j];
    float bj = bfc[j];
    __syncthreads();

    float acc[16];
#pragma unroll
    for (int r = 0; r < 16; r++) acc[r] = bj;
    const float4* hgn4 = (const float4*)hgn;
#pragma unroll
    for (int q4 = 0; q4 < 16; q4++) {
#pragma unroll
        for (int r = 0; r < 16; r++) {
            float4 hv = hgn4[(w * 16 + r) * 16 + q4];
            acc[r] += hv.x * wreg[q4 * 4 + 0] + hv.y * wreg[q4 * 4 + 1]
                    + hv.z * wreg[q4 * 4 + 2] + hv.w * wreg[q4 * 4 + 3];
        }
    }
    float s = 0.f, s2 = 0.f;
#pragma unroll
    for (int r = 0; r < 16; r++) {
        float v = fmaxf(acc[r], 0.f);
        h2[(w * 16 + r) * 64 + j] = v;
        s += v; s2 += v * v;
    }
    red[0][w][j] = s; red[1][w][j] = s2;
    __syncthreads();

    if (t < 64) {
        float su = 0.f, sq = 0.f;
#pragma unroll
        for (int k = 0; k < 8; k++) { su += red[0][k][t]; sq += red[1][k][t]; }
        float mu = su * (1.f / 128.f);
        float var = sq * (1.f / 128.f) - mu * mu;
        float av = g2[t] * rsqrtf(var + EPSBN);
        a[t] = av; cc[t] = b2[t] - mu * av;
    }
    __syncthreads();
    for (int i = t; i < 8192; i += 512) h2[i] = h2[i] * a[i & 63] + cc[i & 63];
    __syncthreads();

    for (int idx = t; idx < 1280; idx += 512) {
        int row = idx / 10, o = idx - row * 10;
        float v = bcls[o];
#pragma unroll
        for (int q = 0; q < 64; q++) v += h2[row * 64 + q] * Wc[q * 10 + o];
        logits[idx] = v;
    }
    __syncthreads();
    if (t < 128) {
        float mx = -1e30f;
#pragma unroll
        for (int o = 0; o < 10; o++) mx = fmaxf(mx, logits[t * 10 + o]);
        float se = 0.f;
#pragma unroll
        for (int o = 0; o < 10; o++) se += expf(logits[t * 10 + o] - mx);
        lse[t] = mx + logf(se);
    }
    __syncthreads();
    for (int idx = t; idx < 1280; idx += 512) out[idx] = logits[idx] - lse[idx / 10];
}

// ---------------- launcher ----------------

extern "C" void kernel_launch(void* const* d_in, const int* in_sizes, int n_in,
                              void* d_out, int out_size, void* d_ws, size_t ws_size,
                              hipStream_t stream) {
    const float* x         = (const float*)d_in[0];
    const int*   ei        = (const int*)  d_in[1];
    const int*   batch     = (const int*)  d_in[2];
    const float* bn_feat_g = (const float*)d_in[3];
    const float* bn_feat_b = (const float*)d_in[4];
    const float* W_feat    = (const float*)d_in[5];
    const float* b_feat    = (const float*)d_in[6];
    const float* conv_bn_g = (const float*)d_in[7];
    const float* conv_bn_b = (const float*)d_in[8];
    const float* conv_W    = (const float*)d_in[9];
    const float* conv_b    = (const float*)d_in[10];
    const float* bn_fc_g   = (const float*)d_in[11];
    const float* bn_fc_b   = (const float*)d_in[12];
    const float* W_fc      = (const float*)d_in[13];
    const float* b_fc      = (const float*)d_in[14];
    const float* bn_hid_g  = (const float*)d_in[15];
    const float* bn_hid_b  = (const float*)d_in[16];
    const float* W_cls     = (const float*)d_in[17];
    const float* b_cls     = (const float*)d_in[18];
    float* out = (float*)d_out;

    float* ws   = (float*)d_ws;
    float* hbuf = ws;                         // 6,400,000 f
    __half* u   = (__half*)(ws + 6400000);    // 6,400,000 halves = 3,200,000 f-slots
    float* dis  = ws + 9600000;               // 100,000 f
    float* Wt   = ws + 9700000;               // 4096 f
    float* bt   = Wt + 4096;                  // 64 f
    float* hg   = bt + 64;                    // 8192 f
    float* sums = hg + 8192;                  // 640 f  (sx, s0, s1, s2, s3)
    int*   cnt  = (int*)(sums + 640);         // 100,000 i
    int*   ecsr = cnt + 100000;               // 6,400,000 i (100k * 64)
    int*   pdeg = (int*)u;                    // 3,200,000 i scratch; dead before u written

    float* sx = sums;
    float* s0 = sums + 128;
    float* s1 = sums + 256;
    float* s2 = sums + 384;
    float* s3 = sums + 512;

    const int* srcp = ei;
    const int* dstp = ei + N_EDGES;

    // zero sums + cnt in one contiguous memset
    hipMemsetAsync(sums, 0, (640 + 100000) * sizeof(float), stream);

    // CSR build (1 atomic/edge) + LDS-privatized out-degree histogram -> dis
    k_build<<<(N_EDGES + 255) / 256, 256, 0, stream>>>(srcp, dstp, cnt, ecsr);
    k_hist<<<HG_SEG * HG_G, 256, 0, stream>>>(srcp, pdeg);
    k_degsum<<<(N_NODES + 255) / 256, 256, 0, stream>>>(pdeg, dis);

    // feature layer: stats on x -> fold -> GEMM+relu (stats of h1 -> s0)
    k_stats<<<512, 256, 0, stream>>>(x, sx);
    k_fold<<<1, 256, 0, stream>>>(sx, bn_feat_g, bn_feat_b, W_feat, b_feat, 1, Wt, bt);
    k_gemm2<<<2048, 256, 0, stream>>>(x, Wt, bt, hbuf, s0, 1);

    // 3 GCN conv layers via commuted agg+GEMM fusion:
    //   u = dis * BN_l(h)  (fp16)  ->  h' = relu((S u) @ W_l + b_l)
    const float* lsums[4] = { s0, s1, s2, s3 };
    for (int l = 0; l < 3; l++) {
        k_uprep<<<512, 256, 0, stream>>>(hbuf, lsums[l], conv_bn_g + l * 64,
                                         conv_bn_b + l * 64, dis, u);
        k_aggemm<<<2048, 256, 0, stream>>>(u, dis, cnt, ecsr, conv_W + l * 4096,
                                           conv_b + l * 64, hbuf,
                                           (float*)lsums[l + 1], l < 2 ? 1 : 0);
    }

    // pooling (+ BN-fc stats) + tail
    k_pool<<<GRAPHS, 256, 0, stream>>>(hbuf, batch, hg, s3);
    k_tail<<<1, 512, 0, stream>>>(hg, s3, bn_fc_g, bn_fc_b, W_fc, b_fc,
                                  bn_hid_g, bn_hid_b, W_cls, b_cls, out);
}

// Round 14
// 672.618 us; speedup vs baseline: 3.1511x; 1.0274x over previous
//
#include <hip/hip_runtime.h>
#include <hip/hip_fp16.h>

#define N_NODES 100000
#define N_EDGES 1200000
#define GRAPHS 128
#define EPSBN 1e-5f
#define HG_G 32     // histogram blocks per segment
#define HG_SEG 4    // segments of 25000 bins (100 KB LDS each)
#define HG_BINS 25000

// ---------------- bucketed CSR build: ONE atomic per edge ----------------

__global__ __launch_bounds__(256) void k_build(const int* __restrict__ src,
                                               const int* __restrict__ dst,
                                               int* __restrict__ cnt,
                                               int* __restrict__ ecsr) {
    int e = blockIdx.x * 256 + threadIdx.x;
    if (e < N_EDGES) {
        int s = src[e], d = dst[e];
        int p = atomicAdd(&cnt[d], 1);
        ecsr[(d << 6) + p] = s;
    }
}

// ---------------- out-degree histogram: LDS-privatized, no global atomics ----------------

__global__ __launch_bounds__(256) void k_hist(const int* __restrict__ src,
                                              int* __restrict__ pdeg) {
    __shared__ int bins[HG_BINS];
    int t = threadIdx.x;
    int seg = blockIdx.x / HG_G, g = blockIdx.x % HG_G;
    for (int i = t; i < HG_BINS; i += 256) bins[i] = 0;
    __syncthreads();
    int lo = seg * HG_BINS, hi = lo + HG_BINS;
    const int chunk = N_EDGES / HG_G;   // 37500 exact
    int e0 = g * chunk, e1 = e0 + chunk;
    for (int e = e0 + t; e < e1; e += 256) {
        int s = src[e];
        if (s >= lo && s < hi) atomicAdd(&bins[s - lo], 1);
    }
    __syncthreads();
    for (int i = t; i < HG_BINS; i += 256)
        pdeg[(seg * HG_G + g) * HG_BINS + i] = bins[i];
}

__global__ __launch_bounds__(256) void k_degsum(const int* __restrict__ pdeg,
                                                float* __restrict__ dis) {
    int i = blockIdx.x * 256 + threadIdx.x;
    if (i >= N_NODES) return;
    int seg = i / HG_BINS, loc = i - seg * HG_BINS;
    int s = 0;
#pragma unroll
    for (int g = 0; g < HG_G; g++) s += pdeg[(seg * HG_G + g) * HG_BINS + loc];
    dis[i] = rsqrtf((float)s + 1.0f);   // +1 self-loop
}

// ---------------- sigma[d] = dis[d] * (sum_in dis[s] + dis[d]) — layer-invariant ----------------

__global__ __launch_bounds__(256) void k_sigma(const float* __restrict__ dis,
                                               const int* __restrict__ cnt,
                                               const int* __restrict__ ecsr,
                                               float* __restrict__ sigma) {
    int lane = threadIdx.x & 63;
    int wid = threadIdx.x >> 6;
    for (int node = blockIdx.x * 4 + wid; node < N_NODES; node += gridDim.x * 4) {
        int m = cnt[node];
        int sraw = ecsr[(node << 6) + lane];
        int sL = (lane < m) ? sraw : 0;
        float v = (lane < m) ? dis[sL] : 0.f;
#pragma unroll
        for (int d = 1; d <= 32; d <<= 1) v += __shfl_xor(v, d, 64);
        if (lane == 0) {
            float dd = dis[node];
            sigma[node] = dd * (v + dd);
        }
    }
}

// ---------------- BN stats over x: float4 loads, LDS reduce ----------------

__global__ __launch_bounds__(256) void k_stats(const float* __restrict__ x,
                                               float* __restrict__ sums) {
    const float4* x4 = (const float4*)x;
    int t = threadIdx.x;
    int q = t & 15, rg = t >> 4;
    float4 s = {0.f, 0.f, 0.f, 0.f}, s2 = {0.f, 0.f, 0.f, 0.f};
    for (int r = blockIdx.x * 16 + rg; r < N_NODES; r += gridDim.x * 16) {
        float4 v = x4[r * 16 + q];
        s.x += v.x; s.y += v.y; s.z += v.z; s.w += v.w;
        s2.x += v.x * v.x; s2.y += v.y * v.y; s2.z += v.z * v.z; s2.w += v.w * v.w;
    }
    __shared__ float red[2][16][64];
    red[0][rg][q * 4 + 0] = s.x;  red[0][rg][q * 4 + 1] = s.y;
    red[0][rg][q * 4 + 2] = s.z;  red[0][rg][q * 4 + 3] = s.w;
    red[1][rg][q * 4 + 0] = s2.x; red[1][rg][q * 4 + 1] = s2.y;
    red[1][rg][q * 4 + 2] = s2.z; red[1][rg][q * 4 + 3] = s2.w;
    __syncthreads();
    if (t < 64) {
        float a = 0.f, b = 0.f;
#pragma unroll
        for (int k = 0; k < 16; k++) { a += red[0][k][t]; b += red[1][k][t]; }
        atomicAdd(&sums[t], a);
        atomicAdd(&sums[64 + t], b);
    }
}

// ---------------- fold BN into GEMM: W' = diag(a)W, b' = c@W (+bias) ----------------

__global__ __launch_bounds__(256) void k_fold(const float* __restrict__ sums, const float* __restrict__ g,
                       const float* __restrict__ b, const float* __restrict__ W,
                       const float* __restrict__ bias_in, int has_bias,
                       float* __restrict__ Wout, float* __restrict__ bout) {
    __shared__ float a[64], cc[64];
    int t = threadIdx.x;
    if (t < 64) {
        float mu = sums[t] * (1.0f / N_NODES);
        float var = sums[64 + t] * (1.0f / N_NODES) - mu * mu;
        float av = g[t] * rsqrtf(var + EPSBN);
        a[t] = av;
        cc[t] = b[t] - mu * av;
    }
    __syncthreads();
    for (int i = t; i < 4096; i += 256) Wout[i] = a[i >> 6] * W[i];
    if (t < 64) {
        float acc = has_bias ? bias_in[t] : 0.0f;
        for (int k = 0; k < 64; k++) acc += cc[k] * W[k * 64 + t];
        bout[t] = acc;
    }
}

// ---------------- feature GEMM: u = dis * relu(X@W + bias) fp16, fused output stats ----------------

__global__ __launch_bounds__(256) void k_gemm2(const float* __restrict__ X, const float* __restrict__ W,
                        const float* __restrict__ bias, const float* __restrict__ dis,
                        __half* __restrict__ U,
                        float* __restrict__ sums, int do_stats) {
    int t = threadIdx.x;
    int j = t & 63;
    int rg = t >> 6;
    float wreg[64];
#pragma unroll
    for (int c = 0; c < 64; c++) wreg[c] = W[c * 64 + j];
    float bj = bias[j];
    __shared__ float xs[16][64];
    float s_sum = 0.f, s_sq = 0.f;
    for (int base = blockIdx.x * 16; base < N_NODES; base += gridDim.x * 16) {
        __syncthreads();
        ((float4*)xs)[t] = ((const float4*)(X + base * 64))[t];
        __syncthreads();
        int r0 = rg * 4;
        float a0 = bj, a1 = bj, a2 = bj, a3 = bj;
#pragma unroll
        for (int c = 0; c < 64; c++) {
            float w = wreg[c];
            a0 += xs[r0 + 0][c] * w;
            a1 += xs[r0 + 1][c] * w;
            a2 += xs[r0 + 2][c] * w;
            a3 += xs[r0 + 3][c] * w;
        }
        a0 = fmaxf(a0, 0.f); a1 = fmaxf(a1, 0.f);
        a2 = fmaxf(a2, 0.f); a3 = fmaxf(a3, 0.f);
        int nb = base + r0;
        U[(nb + 0) * 64 + j] = __float2half_rn(a0 * dis[nb + 0]);
        U[(nb + 1) * 64 + j] = __float2half_rn(a1 * dis[nb + 1]);
        U[(nb + 2) * 64 + j] = __float2half_rn(a2 * dis[nb + 2]);
        U[(nb + 3) * 64 + j] = __float2half_rn(a3 * dis[nb + 3]);
        if (do_stats) {
            s_sum += a0 + a1 + a2 + a3;
            s_sq += a0 * a0 + a1 * a1 + a2 * a2 + a3 * a3;
        }
    }
    if (do_stats) {
        __syncthreads();
        xs[rg][j] = s_sum;
        xs[4 + rg][j] = s_sq;
        __syncthreads();
        if (t < 64) {
            atomicAdd(&sums[t], xs[0][t] + xs[1][t] + xs[2][t] + xs[3][t]);
            atomicAdd(&sums[64 + t], xs[4][t] + xs[5][t] + xs[6][t] + xs[7][t]);
        }
    }
}

// ---------------- fused agg+GEMM with in-kernel BN fold (sigma correction) ----------------
// xs[d] = dis[d](sum_e u[s_e] + u[d])  (raw, u = dis*h)
// h'   = relu( xs @ (diag(a)W) + sigma[d]*(c@W) + b )
// epilogue: !last -> uout = dis*h' (fp16);  last -> hout (f32)

__global__ __launch_bounds__(256) void k_aggemm(const __half* __restrict__ u,
                        const float* __restrict__ dis, const float* __restrict__ sigma,
                        const int* __restrict__ cnt, const int* __restrict__ ecsr,
                        const float* __restrict__ sums_in, const float* __restrict__ bng,
                        const float* __restrict__ bnb,
                        const float* __restrict__ W, const float* __restrict__ bias,
                        __half* __restrict__ uout, float* __restrict__ hout, int last,
                        float* __restrict__ sums_out, int do_stats) {
    const __half2* u2 = (const __half2*)u;
    int t = threadIdx.x;
    int j = t & 63;           // lane; also output column in GEMM phase
    int wid = t >> 6;
    int g = j >> 5, c = j & 31;
    __shared__ float aa[64], ccs[64];
    if (t < 64) {
        float mu = sums_in[t] * (1.0f / N_NODES);
        float var = sums_in[64 + t] * (1.0f / N_NODES) - mu * mu;
        float av = bng[t] * rsqrtf(var + EPSBN);
        aa[t] = av; ccs[t] = bnb[t] - mu * av;
    }
    __syncthreads();
    float wreg[64];
    float cb = 0.f;
#pragma unroll
    for (int q = 0; q < 64; q++) {
        float w = W[q * 64 + j];
        wreg[q] = w * aa[q];
        cb += ccs[q] * w;
    }
    float bj = bias[j];
    __shared__ float xs[16][64];   // wave w owns rows 4w..4w+3 (wave-private)
    float s_sum = 0.f, s_sq = 0.f;
    for (int base = blockIdx.x * 16; base < N_NODES; base += gridDim.x * 16) {
        int r0 = wid * 4;
        float dvals[4], svals[4];
        // ---- phase A: aggregate 4 nodes into wave-private xs rows ----
        for (int r = 0; r < 4; r++) {
            int node = base + r0 + r;
            int m = cnt[node];
            dvals[r] = dis[node];
            svals[r] = sigma[node];
            int sraw = ecsr[(node << 6) + j];
            int sL = (j < m) ? sraw : 0;
            float ax = 0.f, ay = 0.f;
#pragma unroll
            for (int k = 0; k < 8; k++) {
                int e = 2 * k + g;
                int sE = __shfl(sL, e, 64);
                float w = (e < m) ? 1.0f : 0.0f;
                float2 f = __half22float2(u2[sE * 32 + c]);
                ax += w * f.x; ay += w * f.y;
            }
            if (m > 16) {
                for (int e = 16 + g; e < m; e += 2) {
                    int sE = __shfl(sL, e, 64);
                    float2 f = __half22float2(u2[sE * 32 + c]);
                    ax += f.x; ay += f.y;
                }
            }
            ax += __shfl_xor(ax, 32, 64);
            ay += __shfl_xor(ay, 32, 64);
            if (g == 0) {
                float2 sf = __half22float2(u2[node * 32 + c]);
                float dd = dvals[r];
                xs[r0 + r][2 * c + 0] = dd * (ax + sf.x);
                xs[r0 + r][2 * c + 1] = dd * (ay + sf.y);
            }
        }
        // ---- phase B: GEMM + sigma correction (wave-private LDS) ----
        float a0 = bj + svals[0] * cb, a1 = bj + svals[1] * cb;
        float a2 = bj + svals[2] * cb, a3 = bj + svals[3] * cb;
#pragma unroll
        for (int q = 0; q < 64; q++) {
            float w = wreg[q];
            a0 += xs[r0 + 0][q] * w;
            a1 += xs[r0 + 1][q] * w;
            a2 += xs[r0 + 2][q] * w;
            a3 += xs[r0 + 3][q] * w;
        }
        a0 = fmaxf(a0, 0.f); a1 = fmaxf(a1, 0.f);
        a2 = fmaxf(a2, 0.f); a3 = fmaxf(a3, 0.f);
        int nb = base + r0;
        if (last) {
            hout[(nb + 0) * 64 + j] = a0;
            hout[(nb + 1) * 64 + j] = a1;
            hout[(nb + 2) * 64 + j] = a2;
            hout[(nb + 3) * 64 + j] = a3;
        } else {
            uout[(nb + 0) * 64 + j] = __float2half_rn(a0 * dvals[0]);
            uout[(nb + 1) * 64 + j] = __float2half_rn(a1 * dvals[1]);
            uout[(nb + 2) * 64 + j] = __float2half_rn(a2 * dvals[2]);
            uout[(nb + 3) * 64 + j] = __float2half_rn(a3 * dvals[3]);
        }
        if (do_stats) {
            s_sum += a0 + a1 + a2 + a3;
            s_sq += a0 * a0 + a1 * a1 + a2 * a2 + a3 * a3;
        }
    }
    if (do_stats) {
        __syncthreads();
        xs[wid][j] = s_sum;
        xs[4 + wid][j] = s_sq;
        __syncthreads();
        if (t < 64) {
            atomicAdd(&sums_out[t], xs[0][t] + xs[1][t] + xs[2][t] + xs[3][t]);
            atomicAdd(&sums_out[64 + t], xs[4][t] + xs[5][t] + xs[6][t] + xs[7][t]);
        }
    }
}

// ---------------- global_add_pool + fused BN-fc stats ----------------

__global__ __launch_bounds__(256) void k_pool(const float* __restrict__ h, const int* __restrict__ batch,
                       float* __restrict__ hg, float* __restrict__ sums) {
    int g = blockIdx.x;
    int lo = 0, hi = N_NODES;
    while (lo < hi) { int m = (lo + hi) >> 1; if (batch[m] < g) lo = m + 1; else hi = m; }
    int start = lo;
    lo = start; hi = N_NODES;
    while (lo < hi) { int m = (lo + hi) >> 1; if (batch[m] < g + 1) lo = m + 1; else hi = m; }
    int end = lo;
    int c = threadIdx.x & 63, rg = threadIdx.x >> 6;
    float s = 0.f;
    for (int r = start + rg; r < end; r += 4) s += h[r * 64 + c];
    __shared__ float ls[4][64];
    ls[rg][c] = s;
    __syncthreads();
    if (rg == 0) {
        float v = ls[0][c] + ls[1][c] + ls[2][c] + ls[3][c];
        hg[g * 64 + c] = v;
        atomicAdd(&sums[c], v);
        atomicAdd(&sums[64 + c], v * v);
    }
}

// ---------------- tail: BN -> FC+relu -> BN -> classifier -> log_softmax ----------------

__global__ __launch_bounds__(512) void k_tail(const float* __restrict__ hg_in, const float* __restrict__ sums,
                       const float* __restrict__ g1, const float* __restrict__ b1,
                       const float* __restrict__ Wfc, const float* __restrict__ bfc,
                       const float* __restrict__ g2, const float* __restrict__ b2,
                       const float* __restrict__ Wcls, const float* __restrict__ bcls,
                       float* __restrict__ out) {
    __shared__ float hgn[8192];
    __shared__ float h2[8192];
    __shared__ float red[2][8][64];
    __shared__ float a[64], cc[64];
    __shared__ float Wc[640];
    __shared__ float logits[1280];
    __shared__ float lse[128];
    int t = threadIdx.x;
    int j = t & 63;
    int w = t >> 6;

    if (t < 64) {
        float mu = sums[t] * (1.f / 128.f);
        float var = sums[64 + t] * (1.f / 128.f) - mu * mu;
        float av = g1[t] * rsqrtf(var + EPSBN);
        a[t] = av; cc[t] = b1[t] - mu * av;
    }
    for (int i = t; i < 640; i += 512) Wc[i] = Wcls[i];
    __syncthreads();
    for (int i = t; i < 8192; i += 512) hgn[i] = hg_in[i] * a[i & 63] + cc[i & 63];

    float wreg[64];
#pragma unroll
    for (int q = 0; q < 64; q++) wreg[q] = Wfc[q * 64 + j];
    float bj = bfc[j];
    __syncthreads();

    float acc[16];
#pragma unroll
    for (int r = 0; r < 16; r++) acc[r] = bj;
    const float4* hgn4 = (const float4*)hgn;
#pragma unroll
    for (int q4 = 0; q4 < 16; q4++) {
#pragma unroll
        for (int r = 0; r < 16; r++) {
            float4 hv = hgn4[(w * 16 + r) * 16 + q4];
            acc[r] += hv.x * wreg[q4 * 4 + 0] + hv.y * wreg[q4 * 4 + 1]
                    + hv.z * wreg[q4 * 4 + 2] + hv.w * wreg[q4 * 4 + 3];
        }
    }
    float s = 0.f, s2 = 0.f;
#pragma unroll
    for (int r = 0; r < 16; r++) {
        float v = fmaxf(acc[r], 0.f);
        h2[(w * 16 + r) * 64 + j] = v;
        s += v; s2 += v * v;
    }
    red[0][w][j] = s; red[1][w][j] = s2;
    __syncthreads();

    if (t < 64) {
        float su = 0.f, sq = 0.f;
#pragma unroll
        for (int k = 0; k < 8; k++) { su += red[0][k][t]; sq += red[1][k][t]; }
        float mu = su * (1.f / 128.f);
        float var = sq * (1.f / 128.f) - mu * mu;
        float av = g2[t] * rsqrtf(var + EPSBN);
        a[t] = av; cc[t] = b2[t] - mu * av;
    }
    __syncthreads();
    for (int i = t; i < 8192; i += 512) h2[i] = h2[i] * a[i & 63] + cc[i & 63];
    __syncthreads();

    for (int idx = t; idx < 1280; idx += 512) {
        int row = idx / 10, o = idx - row * 10;
        float v = bcls[o];
#pragma unroll
        for (int q = 0; q < 64; q++) v += h2[row * 64 + q] * Wc[q * 10 + o];
        logits[idx] = v;
    }
    __syncthreads();
    if (t < 128) {
        float mx = -1e30f;
#pragma unroll
        for (int o = 0; o < 10; o++) mx = fmaxf(mx, logits[t * 10 + o]);
        float se = 0.f;
#pragma unroll
        for (int o = 0; o < 10; o++) se += expf(logits[t * 10 + o] - mx);
        lse[t] = mx + logf(se);
    }
    __syncthreads();
    for (int idx = t; idx < 1280; idx += 512) out[idx] = logits[idx] - lse[idx / 10];
}

// ---------------- launcher ----------------

extern "C" void kernel_launch(void* const* d_in, const int* in_sizes, int n_in,
                              void* d_out, int out_size, void* d_ws, size_t ws_size,
                              hipStream_t stream) {
    const float* x         = (const float*)d_in[0];
    const int*   ei        = (const int*)  d_in[1];
    const int*   batch     = (const int*)  d_in[2];
    const float* bn_feat_g = (const float*)d_in[3];
    const float* bn_feat_b = (const float*)d_in[4];
    const float* W_feat    = (const float*)d_in[5];
    const float* b_feat    = (const float*)d_in[6];
    const float* conv_bn_g = (const float*)d_in[7];
    const float* conv_bn_b = (const float*)d_in[8];
    const float* conv_W    = (const float*)d_in[9];
    const float* conv_b    = (const float*)d_in[10];
    const float* bn_fc_g   = (const float*)d_in[11];
    const float* bn_fc_b   = (const float*)d_in[12];
    const float* W_fc      = (const float*)d_in[13];
    const float* b_fc      = (const float*)d_in[14];
    const float* bn_hid_g  = (const float*)d_in[15];
    const float* bn_hid_b  = (const float*)d_in[16];
    const float* W_cls     = (const float*)d_in[17];
    const float* b_cls     = (const float*)d_in[18];
    float* out = (float*)d_out;

    float* ws    = (float*)d_ws;
    float* hbuf  = ws;                          // 6,400,000 f (final layer h only)
    __half* u_a  = (__half*)(ws + 6400000);     // 6.4M halves
    __half* u_b  = (__half*)(ws + 9600000);     // 6.4M halves
    float* dis   = ws + 12800000;               // 100,000 f
    float* sigma = ws + 12900000;               // 100,000 f
    float* Wt    = ws + 13000000;               // 4096 f
    float* bt    = Wt + 4096;                   // 64 f
    float* hg    = bt + 64;                     // 8192 f
    float* sums  = hg + 8192;                   // 640 f (sx, s0, s1, s2, s3)
    int*   cnt   = (int*)(sums + 640);          // 100,000 i
    int*   ecsr  = cnt + 100000;                // 6,400,000 i
    int*   pdeg  = (int*)u_b;                   // 3.2M i scratch; dead before u_b written

    float* sx = sums;
    float* s0 = sums + 128;
    float* s1 = sums + 256;
    float* s2 = sums + 384;
    float* s3 = sums + 512;

    const int* srcp = ei;
    const int* dstp = ei + N_EDGES;

    // zero sums + cnt in one contiguous memset
    hipMemsetAsync(sums, 0, (640 + 100000) * sizeof(float), stream);

    // CSR build + histogram -> dis -> sigma
    k_build<<<(N_EDGES + 255) / 256, 256, 0, stream>>>(srcp, dstp, cnt, ecsr);
    k_hist<<<HG_SEG * HG_G, 256, 0, stream>>>(srcp, pdeg);
    k_degsum<<<(N_NODES + 255) / 256, 256, 0, stream>>>(pdeg, dis);
    k_sigma<<<1024, 256, 0, stream>>>(dis, cnt, ecsr, sigma);

    // feature layer: stats on x -> fold -> GEMM+relu -> u0 (fp16, dis-scaled), stats -> s0
    k_stats<<<512, 256, 0, stream>>>(x, sx);
    k_fold<<<1, 256, 0, stream>>>(sx, bn_feat_g, bn_feat_b, W_feat, b_feat, 1, Wt, bt);
    k_gemm2<<<2048, 256, 0, stream>>>(x, Wt, bt, dis, u_a, s0, 1);

    // 3 GCN conv layers: aggemm with in-kernel BN fold + sigma correction, u double-buffered
    k_aggemm<<<2048, 256, 0, stream>>>(u_a, dis, sigma, cnt, ecsr,
                                       s0, conv_bn_g + 0, conv_bn_b + 0,
                                       conv_W + 0, conv_b + 0,
                                       u_b, nullptr, 0, s1, 1);
    k_aggemm<<<2048, 256, 0, stream>>>(u_b, dis, sigma, cnt, ecsr,
                                       s1, conv_bn_g + 64, conv_bn_b + 64,
                                       conv_W + 4096, conv_b + 64,
                                       u_a, nullptr, 0, s2, 1);
    k_aggemm<<<2048, 256, 0, stream>>>(u_a, dis, sigma, cnt, ecsr,
                                       s2, conv_bn_g + 128, conv_bn_b + 128,
                                       conv_W + 8192, conv_b + 128,
                                       nullptr, hbuf, 1, nullptr, 0);

    // pooling (+ BN-fc stats) + tail
    k_pool<<<GRAPHS, 256, 0, stream>>>(hbuf, batch, hg, s3);
    k_tail<<<1, 512, 0, stream>>>(hg, s3, bn_fc_g, bn_fc_b, W_fc, b_fc,
                                  bn_hid_g, bn_hid_b, W_cls, b_cls, out);
}